// Round 4
// baseline (311.247 us; speedup 1.0000x reference)
//
#include <hip/hip_runtime.h>

typedef unsigned short u16;
typedef __bf16 bf16x8 __attribute__((ext_vector_type(8)));
typedef float f32x4 __attribute__((ext_vector_type(4)));

#define HH  56
#define WW  56
#define HW  3136      // 56*56
#define CC  256
#define NB  8
#define CKP 2048      // c*7 padded to c*8 so each channel's 7 taps are one 16B chunk
#define KS1 4         // split-K factor GEMM1 (49 iters -> 12/12/12/13)
#define KS2 2         // split-K factor GEMM2 (32 iters -> 16/16)

// round-to-nearest-even fp32 -> bf16 (bit pattern)
__device__ __forceinline__ u16 f2bf(float f) {
  unsigned int u = __float_as_uint(f);
  u += 0x7fffu + ((u >> 16) & 1u);
  return (u16)(u >> 16);
}
__device__ __forceinline__ float bf2f(u16 v) {
  return __uint_as_float((unsigned)v << 16);
}

// async global->LDS, 16B per lane; LDS dest is wave-uniform base + lane*16
__device__ __forceinline__ void lds_load16(const void* g, void* l) {
  __builtin_amdgcn_global_load_lds(
      (const __attribute__((address_space(1))) void*)g,
      (__attribute__((address_space(3))) void*)l, 16, 0, 0);
}

// ---------------------------------------------------------------------------
// pass1: t1b = bf16(p1w * x), xb = bf16(x).  Fully coalesced float4 reads.
// grid = N*C*HW/4/256 = 6272 blocks
// ---------------------------------------------------------------------------
__global__ void pass1(const float* __restrict__ x, const float* __restrict__ p1w,
                      u16* __restrict__ t1b, u16* __restrict__ xb) {
  int i = blockIdx.x * 256 + threadIdx.x;        // over N*C*HW/4
  int cw = i % (CC * HW / 4);                    // p1w broadcast over n
  float4 xv = ((const float4*)x)[i];
  float4 wv = ((const float4*)p1w)[cw];
  uint2 xo = make_uint2((unsigned)f2bf(xv.x) | ((unsigned)f2bf(xv.y) << 16),
                        (unsigned)f2bf(xv.z) | ((unsigned)f2bf(xv.w) << 16));
  ((uint2*)xb)[i] = xo;
  uint2 to = make_uint2((unsigned)f2bf(xv.x * wv.x) | ((unsigned)f2bf(xv.y * wv.y) << 16),
                        (unsigned)f2bf(xv.z * wv.z) | ((unsigned)f2bf(xv.w * wv.w) << 16));
  ((uint2*)t1b)[i] = to;
}

// ---------------------------------------------------------------------------
// pass2: t5[n][j*8+k][p] = bf16(t1[n,j,p] - t1[n,(j-1)%C, h, w+k-3 (0-pad)])
// k = 0..6; pad rows j*8+7 left untouched (finite poison, zeroed in reduce1).
// grid = N*C*HW/256 = 25088
// ---------------------------------------------------------------------------
__global__ void pass2(const u16* __restrict__ t1b, u16* __restrict__ t5) {
  int idx = blockIdx.x * 256 + threadIdx.x;
  int p   = idx % HW;
  int rem = idx / HW;            // n*C + j
  int j   = rem & (CC - 1);
  int n   = rem >> 8;
  int h = p / WW, w = p - h * WW;
  int jm = (j + CC - 1) & (CC - 1);
  const u16* t1n  = t1b + (long)(n * CC) * HW;
  float a         = bf2f(t1n[(long)j * HW + p]);
  const u16* rowm = t1n + (long)jm * HW + h * WW;
  u16* out = t5 + ((long)n * CKP + j * 8) * HW + p;
#pragma unroll
  for (int k = 0; k < 7; ++k) {
    int tap = w + k - 3;
    float t3v = ((unsigned)tap < (unsigned)WW) ? bf2f(rowm[tap]) : 0.f;
    out[(long)k * HW] = f2bf(a - t3v);
  }
}

// ---------------------------------------------------------------------------
// pass3 (LDS transpose): t6T[n][p][j*8+k] =
//   bf16(x[n,j,p] + t1[n,(j-1)%C,(h-1)%56,((w+1)%56)+k-3]),  slot 7 = 0.
// Block = (8 p-values, n); 256 thr = 8 p-lanes x 32 j-subs.
// grid = (HW/8=392, NB)
// ---------------------------------------------------------------------------
#define P3P  8                  // p-values per block
#define P3S  (CKP + 8)          // LDS row stride in u16
__global__ __launch_bounds__(256)
void pass3(const float* __restrict__ x, const u16* __restrict__ t1b,
           u16* __restrict__ t6T) {
  __shared__ u16 tile[P3P * P3S];   // 32.9 KB
  const int n  = blockIdx.y;
  const int p0 = blockIdx.x * P3P;
  const int t  = threadIdx.x;

  // ---- phase 1: compute, lanes along p ----
  {
    const int pl = t & (P3P - 1);       // p lane 0..7
    const int js = t >> 3;              // j sub 0..31
    const int p  = p0 + pl;
    const int h  = p / WW, w = p - h * WW;
    const int h2 = (h + HH - 1) % HH;   // roll +1 on h: source row h-1
    const int w2 = (w + 1) % WW;        // roll -1 on w: source col w+1
    const float* xn = x   + (long)n * CC * HW;
    const u16* t1n  = t1b + (long)n * CC * HW;
#pragma unroll
    for (int jo = 0; jo < CC / 32; ++jo) {
      const int j  = jo * 32 + js;
      const int jm = (j + CC - 1) & (CC - 1);
      const float xv  = xn[(long)j * HW + p];
      const u16* rowm = t1n + (long)jm * HW + h2 * WW;
      u16 v[8];
#pragma unroll
      for (int k = 0; k < 7; ++k) {
        int tap = w2 + k - 3;
        float t4v = ((unsigned)tap < (unsigned)WW) ? bf2f(rowm[tap]) : 0.f;
        v[k] = f2bf(xv + t4v);
      }
      v[7] = 0;
      uint4 q = make_uint4(v[0] | ((unsigned)v[1] << 16),
                           v[2] | ((unsigned)v[3] << 16),
                           v[4] | ((unsigned)v[5] << 16),
                           v[6] | ((unsigned)v[7] << 16));
      *(uint4*)&tile[pl * P3S + j * 8] = q;
    }
  }
  __syncthreads();

  // ---- phase 2: coalesced write-out ----
  {
    const int pp = t >> 5;              // p row 0..7
    const int c  = t & 31;              // chunk lane 0..31
    u16* outp = t6T + ((long)(n * HW + p0 + pp)) * CKP;
    const u16* srcp = &tile[pp * P3S];
#pragma unroll
    for (int ci = 0; ci < 8; ++ci) {
      int chunk = c + ci * 32;          // 256 chunks of 16B per p-row
      *(uint4*)&outp[chunk * 8] = *(const uint4*)&srcp[chunk * 8];
    }
  }
}

// ---------------------------------------------------------------------------
// Split-K NT GEMM, bf16 MFMA 16x16x32, 128x128 tile, BK=64, global_load_lds,
// XOR chunk swizzle.  Writes fp32 partials (no scale): Cp[ks][nb][M][LDC].
// IS1: A=xb(256x3136) B=t5(2048x3136), KS1 splits of 49 iters.
// !IS1: A=t7(256x2048) B=t6T(3136x2048), KS2 splits of 32 iters, col guard.
// grid = (2, N/128, NB*KS)
// ---------------------------------------------------------------------------
template <int IS1, int KS>
__global__ __launch_bounds__(256)
void gemm_nt(const u16* __restrict__ A, const u16* __restrict__ B,
             float* __restrict__ Cp) {
  constexpr int  LDA = IS1 ? HW : CKP;
  constexpr int  LDB = IS1 ? HW : CKP;
  constexpr int  NIT = IS1 ? HW / 64 : CKP / 64;   // 49 : 32 K-iterations
  constexpr int  LDC = IS1 ? CKP : HW;
  constexpr long sA  = IS1 ? (long)CC * HW : (long)CC * CKP;
  constexpr long sB  = IS1 ? (long)CKP * HW : (long)HW * CKP;
  constexpr long sC  = IS1 ? (long)CC * CKP : (long)CC * HW;

  __shared__ u16 As[128 * 64];
  __shared__ u16 Bs[128 * 64];

  const int z  = blockIdx.z;
  const int nb = z / KS, ks = z % KS;
  const int it0 = NIT * ks / KS, it1 = NIT * (ks + 1) / KS;
  const u16* Ab = A + nb * sA;
  const u16* Bb = B + nb * sB;
  const int m0 = blockIdx.x * 128, n0 = blockIdx.y * 128;
  const int t = threadIdx.x;
  const int lane = t & 63, wave = t >> 6;
  const int wm = wave & 1, wn = wave >> 1;     // 2x2 waves, 64x64 each
  const int lm = lane & 15, quad = lane >> 4;

  f32x4 acc[4][4];
#pragma unroll
  for (int a = 0; a < 4; ++a)
#pragma unroll
    for (int b = 0; b < 4; ++b) acc[a][b] = (f32x4)0.0f;

  // staging geometry: 1024 chunks of 16B per tile, 4 per thread.
  int rowc[4], colc[4];
#pragma unroll
  for (int ci = 0; ci < 4; ++ci) {
    int c = t + ci * 256;
    rowc[ci] = c >> 3;
    colc[ci] = ((c & 7) ^ (rowc[ci] & 7)) * 8;   // XOR swizzle breaks bank aliasing
  }

  for (int it = it0; it < it1; ++it) {
    const int k0 = it * 64;
#pragma unroll
    for (int ci = 0; ci < 4; ++ci) {
      int c = t + ci * 256;
      lds_load16(Ab + (long)(m0 + rowc[ci]) * LDA + k0 + colc[ci], &As[c * 8]);
      int br = n0 + rowc[ci];
      if (!IS1) br = br < (HW - 1) ? br : (HW - 1);   // clamp rows past 3135
      lds_load16(Bb + (long)br * LDB + k0 + colc[ci], &Bs[c * 8]);
    }
    __syncthreads();
#pragma unroll
    for (int kk = 0; kk < 2; ++kk) {
      const int phys = ((kk * 4 + quad) ^ (lm & 7)) * 8;  // swizzled chunk, elems
      bf16x8 af[4], bv[4];
#pragma unroll
      for (int mi = 0; mi < 4; ++mi)
        af[mi] = *(const bf16x8*)&As[(wm * 64 + mi * 16 + lm) * 64 + phys];
#pragma unroll
      for (int ni = 0; ni < 4; ++ni)
        bv[ni] = *(const bf16x8*)&Bs[(wn * 64 + ni * 16 + lm) * 64 + phys];
#pragma unroll
      for (int mi = 0; mi < 4; ++mi)
#pragma unroll
        for (int ni = 0; ni < 4; ++ni)
          acc[mi][ni] = __builtin_amdgcn_mfma_f32_16x16x32_bf16(
              af[mi], bv[ni], acc[mi][ni], 0, 0, 0);
    }
    __syncthreads();
  }

  // epilogue: fp32 partial store; C/D layout: col = lane&15, row = quad*4+reg
  float* Cb = Cp + ((long)ks * NB + nb) * sC;
#pragma unroll
  for (int mi = 0; mi < 4; ++mi)
#pragma unroll
    for (int ni = 0; ni < 4; ++ni) {
      int rb = m0 + wm * 64 + mi * 16 + quad * 4;
      int cg = n0 + wn * 64 + ni * 16 + lm;
      if (IS1 || cg < HW) {
#pragma unroll
        for (int r = 0; r < 4; ++r)
          Cb[(long)(rb + r) * LDC + cg] = acc[mi][ni][r];
      }
    }
}

// ---------------------------------------------------------------------------
// reduce1: t7 = bf16((sum of KS1 partials) / 56), pad cols (jk%8==7) = 0.
// float4 per thread.  grid = NB*CC*CKP/4/256 = 4096
// ---------------------------------------------------------------------------
__global__ void reduce1(const float* __restrict__ p1, u16* __restrict__ t7) {
  const int i = blockIdx.x * 256 + threadIdx.x;   // float4 idx over NB*CC*CKP/4
  const long S = (long)NB * CC * CKP / 4;
  float4 a = ((const float4*)p1)[i];
  float4 b = ((const float4*)p1)[i + S];
  float4 c = ((const float4*)p1)[i + 2 * S];
  float4 d = ((const float4*)p1)[i + 3 * S];
  const float s = 1.0f / 56.0f;
  float e0 = (a.x + b.x + c.x + d.x) * s;
  float e1 = (a.y + b.y + c.y + d.y) * s;
  float e2 = (a.z + b.z + c.z + d.z) * s;
  float e3 = (a.w + b.w + c.w + d.w) * s;
  u16 w3 = (i & 1) ? (u16)0 : f2bf(e3);   // col%8==7 lives at elem3 of odd float4s
  ushort4 o = make_ushort4(f2bf(e0), f2bf(e1), f2bf(e2), w3);
  ((ushort4*)t7)[i] = o;
}

// ---------------------------------------------------------------------------
// reduce2: d_out = (sum of KS2 partials) / sqrt(1792).  fp32 float4.
// grid = NB*CC*HW/4/256 = 6272
// ---------------------------------------------------------------------------
__global__ void reduce2(const float* __restrict__ p2, float* __restrict__ out) {
  const int i = blockIdx.x * 256 + threadIdx.x;   // float4 idx over NB*CC*HW/4
  const long S = (long)NB * CC * HW / 4;
  float4 a = ((const float4*)p2)[i];
  float4 b = ((const float4*)p2)[i + S];
  const float s = 0.023622783f;
  float4 o;
  o.x = (a.x + b.x) * s; o.y = (a.y + b.y) * s;
  o.z = (a.z + b.z) * s; o.w = (a.w + b.w) * s;
  ((float4*)out)[i] = o;
}

// ---------------------------------------------------------------------------
// Pipeline: pass1 -> pass2 -> gemm1 -> reduce1 -> pass3 -> gemm2 -> reduce2
// Aliasing (stream-ordered, proven ws bound 252.4 MB; footprint 239.7 MB):
//   p1 (67.1 MB fp32 partials) aliases t6T region (written later by pass3)
//   p2 (51.4 MB fp32 partials) aliases t5 region (dead after gemm1)
// ---------------------------------------------------------------------------
extern "C" void kernel_launch(void* const* d_in, const int* in_sizes, int n_in,
                              void* d_out, int out_size, void* d_ws, size_t ws_size,
                              hipStream_t stream) {
  const float* x   = (const float*)d_in[0];   // (8,256,56,56)
  const float* p1w = (const float*)d_in[1];   // (1,256,56,56)

  char* ws = (char*)d_ws;
  size_t o = 0;
  u16* xb  = (u16*)(ws + o); o += (size_t)NB * CC * HW * 2;   //  12.8 MB
  u16* t5  = (u16*)(ws + o); o += (size_t)NB * CKP * HW * 2;  // 102.8 MB
  u16* t6T = (u16*)(ws + o); o += (size_t)NB * HW * CKP * 2;  // 102.8 MB
  u16* t7  = (u16*)(ws + o); o += (size_t)NB * CC * CKP * 2;  //   8.4 MB
  u16* t1b = (u16*)(ws + o); o += (size_t)NB * CC * HW * 2;   //  12.8 MB
  float* p1 = (float*)t6T;   // KS1*NB*CC*CKP*4 = 67.1 MB <= 102.8
  float* p2 = (float*)t5;    // KS2*NB*CC*HW*4  = 51.4 MB <= 102.8

  pass1<<<NB * CC * HW / 4 / 256, 256, 0, stream>>>(x, p1w, t1b, xb);
  pass2<<<NB * CC * HW / 256, 256, 0, stream>>>(t1b, t5);
  gemm_nt<1, KS1><<<dim3(2, CKP / 128, NB * KS1), 256, 0, stream>>>(xb, t5, p1);
  reduce1<<<NB * CC * CKP / 4 / 256, 256, 0, stream>>>(p1, t7);
  pass3<<<dim3(HW / P3P, NB), 256, 0, stream>>>(x, t1b, t6T);
  gemm_nt<0, KS2><<<dim3(2, (HW + 127) / 128, NB * KS2), 256, 0, stream>>>(t7, t6T, p2);
  reduce2<<<NB * CC * HW / 4 / 256, 256, 0, stream>>>(p2, (float*)d_out);
}